// Round 2
// baseline (1327.001 us; speedup 1.0000x reference)
//
#include <hip/hip_runtime.h>

// ---- problem constants ----
static constexpr int kN = 64;    // nodes
static constexpr int kD = 1024;  // feature dim
static constexpr int kE = 1024;  // edges (16 per row, row-major sorted)
static constexpr int kT = 2;     // iterations

// =====================================================================
// GEMM: C[M,O] = A[M,K] @ W[O,K]^T   (A rows stride lda, W rows stride ldw)
// tile 64x64, 256 threads, 4x4 per thread, K-step 32.
// KS = split-K factor; C is a partial buffer [KS][M*O] when KS>1.
// =====================================================================
__global__ __launch_bounds__(256)
void k_gemm(const float* __restrict__ A, int lda,
            const float* __restrict__ W, int ldw,
            float* __restrict__ C,
            int M, int O, int K, int KS)
{
    __shared__ float As[32][68];   // [k][m], pad 68 keeps float4 reads aligned + conflict-free
    __shared__ float Bs[32][68];   // [k][o]
    const int tid = threadIdx.x;
    const int tx = tid & 15, ty = tid >> 4;
    const int rowBase = blockIdx.y * 64;
    const int colBase = blockIdx.x * 64;
    const int kchunk = K / KS;
    const int kbeg = blockIdx.z * kchunk;
    const int kend = kbeg + kchunk;

    float acc[4][4] = {};

    const int r  = tid >> 3;        // 0..31
    const int kq = (tid & 7) * 4;   // 0,4,..,28

    for (int kt = kbeg; kt < kend; kt += 32) {
#pragma unroll
        for (int h = 0; h < 2; ++h) {
            const int row = r + h * 32;
            const float4 a4 = *reinterpret_cast<const float4*>(
                A + (size_t)(rowBase + row) * lda + kt + kq);
            As[kq + 0][row] = a4.x; As[kq + 1][row] = a4.y;
            As[kq + 2][row] = a4.z; As[kq + 3][row] = a4.w;
            const float4 b4 = *reinterpret_cast<const float4*>(
                W + (size_t)(colBase + row) * ldw + kt + kq);
            Bs[kq + 0][row] = b4.x; Bs[kq + 1][row] = b4.y;
            Bs[kq + 2][row] = b4.z; Bs[kq + 3][row] = b4.w;
        }
        __syncthreads();
#pragma unroll
        for (int k = 0; k < 32; ++k) {
            const float4 av = *reinterpret_cast<const float4*>(&As[k][ty * 4]);
            const float4 bv = *reinterpret_cast<const float4*>(&Bs[k][tx * 4]);
            acc[0][0] += av.x * bv.x; acc[0][1] += av.x * bv.y;
            acc[0][2] += av.x * bv.z; acc[0][3] += av.x * bv.w;
            acc[1][0] += av.y * bv.x; acc[1][1] += av.y * bv.y;
            acc[1][2] += av.y * bv.z; acc[1][3] += av.y * bv.w;
            acc[2][0] += av.z * bv.x; acc[2][1] += av.z * bv.y;
            acc[2][2] += av.z * bv.z; acc[2][3] += av.z * bv.w;
            acc[3][0] += av.w * bv.x; acc[3][1] += av.w * bv.y;
            acc[3][2] += av.w * bv.z; acc[3][3] += av.w * bv.w;
        }
        __syncthreads();
    }
    float* Cp = C + (size_t)blockIdx.z * (size_t)M * O;
#pragma unroll
    for (int a = 0; a < 4; ++a) {
        const int row = rowBase + ty * 4 + a;
        *reinterpret_cast<float4*>(Cp + (size_t)row * O + colBase + tx * 4) =
            make_float4(acc[a][0], acc[a][1], acc[a][2], acc[a][3]);
    }
}

// reduce split-K partials: C[i] = sum_z P[z][i] (+ bias)
__global__ void k_reduceK(const float* __restrict__ P, float* __restrict__ C,
                          const float* __restrict__ bias, int MO4, int O4, int KS)
{
    int i = blockIdx.x * blockDim.x + threadIdx.x;
    if (i >= MO4) return;
    float4 s = make_float4(0.f, 0.f, 0.f, 0.f);
    for (int z = 0; z < KS; ++z) {
        const float4 v = reinterpret_cast<const float4*>(P)[(size_t)z * MO4 + i];
        s.x += v.x; s.y += v.y; s.z += v.z; s.w += v.w;
    }
    if (bias) {
        const float4 b = reinterpret_cast<const float4*>(bias)[i % O4];
        s.x += b.x; s.y += b.y; s.z += b.z; s.w += b.w;
    }
    reinterpret_cast<float4*>(C)[i] = s;
}

__global__ void k_copy(float* __restrict__ dst, const float* __restrict__ src, int n4)
{
    int i = blockIdx.x * blockDim.x + threadIdx.x;
    if (i < n4) reinterpret_cast<float4*>(dst)[i] = reinterpret_cast<const float4*>(src)[i];
}

// out[r] = [x, c, x*c, (dsign ? c-x : x-c)]  (each width kD)
// reference: node joint uses vctx - visual (dsign=1);
//            rel  joint uses rel_temp - rel_ctx = x - c (dsign=0)  <-- different order!
__global__ void k_joint(const float* __restrict__ x, const float* __restrict__ c,
                        float* __restrict__ out, int R, int dsign)
{
    const int W4 = kD / 4;
    int idx = blockIdx.x * blockDim.x + threadIdx.x;
    if (idx >= R * W4) return;
    const int row = idx / W4, d4 = idx % W4;
    const float4 xv = reinterpret_cast<const float4*>(x)[(size_t)row * W4 + d4];
    const float4 cv = reinterpret_cast<const float4*>(c)[(size_t)row * W4 + d4];
    float4* o = reinterpret_cast<float4*>(out + (size_t)row * 4 * kD);
    o[d4] = xv;
    o[W4 + d4] = cv;
    o[2 * W4 + d4] = make_float4(xv.x * cv.x, xv.y * cv.y, xv.z * cv.z, xv.w * cv.w);
    if (dsign)
        o[3 * W4 + d4] = make_float4(cv.x - xv.x, cv.y - xv.y, cv.z - xv.z, cv.w - xv.w);
    else
        o[3 * W4 + d4] = make_float4(xv.x - cv.x, xv.y - cv.y, xv.z - cv.z, xv.w - cv.w);
}

__global__ void k_concat2(const float* __restrict__ a, const float* __restrict__ b,
                          float* __restrict__ out, int R)
{
    const int W4 = kD / 4;
    int idx = blockIdx.x * blockDim.x + threadIdx.x;
    if (idx >= R * 2 * W4) return;
    const int row = idx / (2 * W4), c = idx % (2 * W4);
    float4 v;
    if (c < W4) v = reinterpret_cast<const float4*>(a)[(size_t)row * W4 + c];
    else        v = reinterpret_cast<const float4*>(b)[(size_t)row * W4 + (c - W4)];
    reinterpret_cast<float4*>(out)[idx] = v;
}

__global__ void k_concat3(const float* __restrict__ a, const float* __restrict__ b,
                          const float* __restrict__ c, float* __restrict__ out, int R)
{
    const int W4 = kD / 4;
    int idx = blockIdx.x * blockDim.x + threadIdx.x;
    if (idx >= R * 3 * W4) return;
    const int row = idx / (3 * W4), cc = idx % (3 * W4);
    float4 v;
    if (cc < W4)          v = reinterpret_cast<const float4*>(a)[(size_t)row * W4 + cc];
    else if (cc < 2 * W4) v = reinterpret_cast<const float4*>(b)[(size_t)row * W4 + (cc - W4)];
    else                  v = reinterpret_cast<const float4*>(c)[(size_t)row * W4 + (cc - 2 * W4)];
    reinterpret_cast<float4*>(out)[idx] = v;
}

// relj[e] += a_s[i_e] + a_o[j_e]
__global__ __launch_bounds__(256)
void k_add_so(float* __restrict__ relj, const float* __restrict__ a_s,
              const float* __restrict__ a_o, const int* __restrict__ edge_idx)
{
    const int e = blockIdx.x, t = threadIdx.x;
    const int idx = edge_idx[e];
    const int i = idx >> 6, j = idx & 63;
    float4* r = reinterpret_cast<float4*>(relj + (size_t)e * kD);
    const float4 s = reinterpret_cast<const float4*>(a_s + (size_t)i * kD)[t];
    const float4 o = reinterpret_cast<const float4*>(a_o + (size_t)j * kD)[t];
    float4 v = r[t];
    v.x += s.x + o.x; v.y += s.y + o.y; v.z += s.z + o.z; v.w += s.w + o.w;
    r[t] = v;
}

// s_sbj[e] = <q_s[i_e], r2s[e]>/32 ; s_obj[e] = <q_o[j_e], r2o[e]>/32
__global__ __launch_bounds__(256)
void k_scores(const float* __restrict__ qs, const float* __restrict__ qo,
              const float* __restrict__ r2s, const float* __restrict__ r2o,
              const int* __restrict__ edge_idx,
              float* __restrict__ s_sbj, float* __restrict__ s_obj)
{
    const int e = blockIdx.x, t = threadIdx.x;
    const int idx = edge_idx[e];
    const int i = idx >> 6, j = idx & 63;
    const float4 a = reinterpret_cast<const float4*>(qs + (size_t)i * kD)[t];
    const float4 b = reinterpret_cast<const float4*>(r2s + (size_t)e * kD)[t];
    const float4 c = reinterpret_cast<const float4*>(qo + (size_t)j * kD)[t];
    const float4 d = reinterpret_cast<const float4*>(r2o + (size_t)e * kD)[t];
    float vs = a.x * b.x + a.y * b.y + a.z * b.z + a.w * b.w;
    float vo = c.x * d.x + c.y * d.y + c.z * d.z + c.w * d.w;
    for (int off = 32; off; off >>= 1) {
        vs += __shfl_down(vs, off);
        vo += __shfl_down(vo, off);
    }
    __shared__ float ss[4], so[4];
    const int w = t >> 6, lane = t & 63;
    if (lane == 0) { ss[w] = vs; so[w] = vo; }
    __syncthreads();
    if (t == 0) {
        s_sbj[e] = (ss[0] + ss[1] + ss[2] + ss[3]) * 0.03125f;
        s_obj[e] = (so[0] + so[1] + so[2] + so[3]) * 0.03125f;
    }
}

// row softmax over the 16 contiguous edges of each row i
__global__ void k_softmax_row(const float* __restrict__ s, float* __restrict__ w)
{
    const int i = blockIdx.x, t = threadIdx.x;  // blockDim = 16
    float v = s[i * 16 + t];
    float m = v;
    for (int off = 8; off; off >>= 1) m = fmaxf(m, __shfl_xor(m, off, 16));
    const float ex = expf(v - m);
    float sum = ex;
    for (int off = 8; off; off >>= 1) sum += __shfl_xor(sum, off, 16);
    w[i * 16 + t] = ex / sum;
}

// column softmax over edges with j_e == j (gathered via conn_map)
__global__ void k_softmax_col(const float* __restrict__ s, const int* __restrict__ conn,
                              float* __restrict__ w)
{
    const int j = blockIdx.x, t = threadIdx.x;  // blockDim = 64, t = row i
    const int e = conn[t * kN + j];
    const float v = (e >= 0) ? s[e] : -1e30f;
    float m = v;
    for (int off = 32; off; off >>= 1) m = fmaxf(m, __shfl_xor(m, off));
    const float ex = (e >= 0) ? expf(v - m) : 0.f;
    float sum = ex;
    for (int off = 32; off; off >>= 1) sum += __shfl_xor(sum, off);
    if (e >= 0) w[e] = ex / sum;
}

// ctx1[i] = sum_{q<16} w[16i+q] * relj[16i+q]
__global__ __launch_bounds__(256)
void k_ctx1(const float* __restrict__ relj, const float* __restrict__ w,
            float* __restrict__ ctx1)
{
    const int i = blockIdx.x, t = threadIdx.x;
    float4 acc = make_float4(0.f, 0.f, 0.f, 0.f);
#pragma unroll
    for (int q = 0; q < 16; ++q) {
        const int e = i * 16 + q;
        const float wv = w[e];
        const float4 v = reinterpret_cast<const float4*>(relj + (size_t)e * kD)[t];
        acc.x += wv * v.x; acc.y += wv * v.y; acc.z += wv * v.z; acc.w += wv * v.w;
    }
    reinterpret_cast<float4*>(ctx1 + (size_t)i * kD)[t] = acc;
}

// ctx2[j] = sum_i (conn[i][j]>=0) w[e] * relj[e]
__global__ __launch_bounds__(256)
void k_ctx2(const float* __restrict__ relj, const float* __restrict__ w,
            const int* __restrict__ conn, float* __restrict__ ctx2)
{
    const int j = blockIdx.x, t = threadIdx.x;
    float4 acc = make_float4(0.f, 0.f, 0.f, 0.f);
    for (int i = 0; i < kN; ++i) {
        const int e = conn[i * kN + j];
        if (e >= 0) {
            const float wv = w[e];
            const float4 v = reinterpret_cast<const float4*>(relj + (size_t)e * kD)[t];
            acc.x += wv * v.x; acc.y += wv * v.y; acc.z += wv * v.z; acc.w += wv * v.w;
        }
    }
    reinterpret_cast<float4*>(ctx2 + (size_t)j * kD)[t] = acc;
}

// =====================================================================
extern "C" void kernel_launch(void* const* d_in, const int* in_sizes, int n_in,
                              void* d_out, int out_size, void* d_ws, size_t ws_size,
                              hipStream_t stream)
{
    const float* visual   = (const float*)d_in[0];
    const float* relvis   = (const float*)d_in[1];
    const int*   conn     = (const int*)d_in[2];
    // d_in[3] = topN_boxes_ids (unused)
    const int*   edge_idx = (const int*)d_in[4];
    const float* W_sub    = (const float*)d_in[5];
    const float* W_obj    = (const float*)d_in[6];
    const float* W_r2s    = (const float*)d_in[7];
    const float* W_r2o    = (const float*)d_in[8];
    const float* W_joint  = (const float*)d_in[9];
    const float* W_ctx    = (const float*)d_in[10];
    const float* W_relu   = (const float*)d_in[11];  // (D,3D): Ws|Wo|Wr
    const float* W_relj   = (const float*)d_in[12];
    const float* W_relc   = (const float*)d_in[13];
    const float* W_node   = (const float*)d_in[14];
    const float* b_node   = (const float*)d_in[15];
    const float* W_factor = (const float*)d_in[16];
    (void)in_sizes; (void)n_in; (void)out_size; (void)ws_size;

    float* ws = (float*)d_ws;
    size_t off = 0;
    auto alloc = [&](size_t n) { float* p = ws + off; off += n; return p; };
    float* vjin   = alloc((size_t)kN * 4 * kD);
    float* bigA   = alloc((size_t)kE * 4 * kD);   // rjin / relctx_in / relout_in
    float* rj     = alloc((size_t)kE * kD);
    float* relj   = alloc((size_t)kE * kD);
    float* r2s    = alloc((size_t)kE * kD);
    float* r2o    = alloc((size_t)kE * kD);
    float* rc     = alloc((size_t)kE * kD);       // rel_ctx at edges
    float* vj     = alloc((size_t)kN * kD);
    float* a_s    = alloc((size_t)kN * kD);
    float* a_o    = alloc((size_t)kN * kD);
    float* q_s    = alloc((size_t)kN * kD);
    float* q_o    = alloc((size_t)kN * kD);
    float* ctx1   = alloc((size_t)kN * kD);
    float* ctx2   = alloc((size_t)kN * kD);
    float* vctx   = alloc((size_t)kN * kD);
    float* vctxin = alloc((size_t)kN * 3 * kD);
    float* voutin = alloc((size_t)kN * 2 * kD);
    float* s_sbj  = alloc(kE);
    float* s_obj  = alloc(kE);
    float* w_sbj  = alloc(kE);
    float* w_obj  = alloc(kE);
    float* part   = alloc(8 * (size_t)kN * kD);   // split-K partials

    auto gemm = [&](const float* A, int lda, const float* W, int ldw, float* C,
                    int M, int O, int K, int KS) {
        dim3 g(O / 64, M / 64, KS);
        hipLaunchKernelGGL(k_gemm, g, dim3(256), 0, stream, A, lda, W, ldw, C, M, O, K, KS);
    };
    auto reduceK = [&](float* C, const float* bias, int KS) {
        hipLaunchKernelGGL(k_reduceK, dim3((kN * kD / 4 + 255) / 256), dim3(256), 0, stream,
                           part, C, bias, kN * kD / 4, kD / 4, KS);
    };

    // init: vctx = visual, rc = rel_visual (rel_temp at edge positions)
    hipLaunchKernelGGL(k_copy, dim3((kN * kD / 4 + 255) / 256), dim3(256), 0, stream,
                       vctx, visual, kN * kD / 4);
    hipLaunchKernelGGL(k_copy, dim3((kE * kD / 4 + 255) / 256), dim3(256), 0, stream,
                       rc, relvis, kE * kD / 4);

    for (int t = 0; t < kT; ++t) {
        // vj = joint(visual, vctx) @ W_joint^T   (4th block = vctx - visual)
        hipLaunchKernelGGL(k_joint, dim3((kN * (kD / 4) + 255) / 256), dim3(256), 0, stream,
                           visual, vctx, vjin, kN, 1);
        gemm(vjin, 4 * kD, W_joint, 4 * kD, part, kN, kD, 4 * kD, 8);
        reduceK(vj, nullptr, 8);
        // rj = joint(rel_temp, rel_ctx) @ W_rel_joint^T  (4th block = rel_temp - rel_ctx)
        hipLaunchKernelGGL(k_joint, dim3((kE * (kD / 4) + 255) / 256), dim3(256), 0, stream,
                           relvis, rc, bigA, kE, 0);
        gemm(bigA, 4 * kD, W_relj, 4 * kD, rj, kE, kD, 4 * kD, 1);
        // a_s = vj@Ws^T, a_o = vj@Wo^T, relj = rj@Wr^T + a_s[i] + a_o[j]
        gemm(vj, kD, W_relu,          3 * kD, part, kN, kD, kD, 8); reduceK(a_s, nullptr, 8);
        gemm(vj, kD, W_relu + kD,     3 * kD, part, kN, kD, kD, 8); reduceK(a_o, nullptr, 8);
        gemm(rj, kD, W_relu + 2 * kD, 3 * kD, relj, kE, kD, kD, 1);
        hipLaunchKernelGGL(k_add_so, dim3(kE), dim3(256), 0, stream, relj, a_s, a_o, edge_idx);
        // attention scores
        gemm(vj, kD, W_sub, kD, part, kN, kD, kD, 8); reduceK(q_s, nullptr, 8);
        gemm(vj, kD, W_obj, kD, part, kN, kD, kD, 8); reduceK(q_o, nullptr, 8);
        gemm(relj, kD, W_r2s, kD, r2s, kE, kD, kD, 1);
        gemm(relj, kD, W_r2o, kD, r2o, kE, kD, kD, 1);
        hipLaunchKernelGGL(k_scores, dim3(kE), dim3(256), 0, stream,
                           q_s, q_o, r2s, r2o, edge_idx, s_sbj, s_obj);
        hipLaunchKernelGGL(k_softmax_row, dim3(kN), dim3(16), 0, stream, s_sbj, w_sbj);
        hipLaunchKernelGGL(k_softmax_col, dim3(kN), dim3(64), 0, stream, s_obj, conn, w_obj);
        // context aggregation
        hipLaunchKernelGGL(k_ctx1, dim3(kN), dim3(256), 0, stream, relj, w_sbj, ctx1);
        hipLaunchKernelGGL(k_ctx2, dim3(kN), dim3(256), 0, stream, relj, w_obj, conn, ctx2);
        // vctx = concat(vctx, ctx1, ctx2) @ W_ctx^T
        hipLaunchKernelGGL(k_concat3, dim3((kN * 3 * (kD / 4) + 255) / 256), dim3(256), 0, stream,
                           vctx, ctx1, ctx2, vctxin, kN);
        gemm(vctxin, 3 * kD, W_ctx, 3 * kD, part, kN, kD, 3 * kD, 8);
        reduceK(vctx, nullptr, 8);
        // rel_ctx = concat(rel_ctx, relj) @ W_rel_ctx^T
        hipLaunchKernelGGL(k_concat2, dim3((kE * 2 * (kD / 4) + 255) / 256), dim3(256), 0, stream,
                           rc, relj, bigA, kE);
        gemm(bigA, 2 * kD, W_relc, 2 * kD, rc, kE, kD, 2 * kD, 1);
    }

    float* rel_out = (float*)d_out;
    float* v_out   = (float*)d_out + (size_t)kE * kD;
    // rel_out = concat(rel_visual, rel_ctx) @ W_factor^T
    hipLaunchKernelGGL(k_concat2, dim3((kE * 2 * (kD / 4) + 255) / 256), dim3(256), 0, stream,
                       relvis, rc, bigA, kE);
    gemm(bigA, 2 * kD, W_factor, 2 * kD, rel_out, kE, kD, 2 * kD, 1);
    // v_out = concat(visual, vctx) @ W_node^T + b_node   (deg>=16 always, no fallback)
    hipLaunchKernelGGL(k_concat2, dim3((kN * 2 * (kD / 4) + 255) / 256), dim3(256), 0, stream,
                       visual, vctx, voutin, kN);
    gemm(voutin, 2 * kD, W_node, 2 * kD, part, kN, kD, 2 * kD, 8);
    reduceK(v_out, b_node, 8);
}

// Round 3
// 424.220 us; speedup vs baseline: 3.1281x; 3.1281x over previous
//
#include <hip/hip_runtime.h>

// ---- problem constants ----
static constexpr int kN = 64;    // nodes
static constexpr int kD = 1024;  // feature dim
static constexpr int kE = 1024;  // edges (16 per row, row-major sorted)
static constexpr int kT = 2;     // iterations

typedef short  bf16x8 __attribute__((ext_vector_type(8)));
typedef float  f32x4  __attribute__((ext_vector_type(4)));
typedef unsigned short us8 __attribute__((ext_vector_type(8)));
typedef unsigned short us4 __attribute__((ext_vector_type(4)));

__device__ __forceinline__ unsigned short f2b(float f) {
    unsigned int u = __builtin_bit_cast(unsigned int, f);
    u += 0x7FFFu + ((u >> 16) & 1u);          // RNE
    return (unsigned short)(u >> 16);
}

// =====================================================================
// bf16 MFMA GEMM: C[M,O] = A[M,K] @ W[O,K]^T, A/W bf16 row-major.
// 64x64 tile, 256 thr (4 waves, 16-row stripe each), BK=64.
// LDS 64x64 bf16, 16B-chunk XOR swizzle (c8 ^ row&7): write & read conflict-free.
// KS>1: write f32 partials at Cf + z*M*O. Cb!=null (KS==1 only): write bf16.
// =====================================================================
__global__ __launch_bounds__(256)
void k_gemm_bf(const unsigned short* __restrict__ A, int lda,
               const unsigned short* __restrict__ W, int ldw,
               float* __restrict__ Cf, unsigned short* __restrict__ Cb,
               int M, int O, int K, int KS)
{
    __shared__ unsigned short As[64][64];
    __shared__ unsigned short Bs[64][64];
    const int tid = threadIdx.x;
    const int lane = tid & 63, wid = tid >> 6;
    const int rowBase = blockIdx.y * 64, colBase = blockIdx.x * 64;
    const int kchunk = K / KS, kbeg = blockIdx.z * kchunk, kend = kbeg + kchunk;

    const int sr = tid >> 3;          // 0..31
    const int sc8 = tid & 7;          // 16B chunk
    const int wc8 = sc8 ^ (sr & 7);   // swizzled chunk (same for sr and sr+32)

    const unsigned short* Ar0 = A + (size_t)(rowBase + sr) * lda;
    const unsigned short* Ar1 = A + (size_t)(rowBase + sr + 32) * lda;
    const unsigned short* Wr0 = W + (size_t)(colBase + sr) * ldw;
    const unsigned short* Wr1 = W + (size_t)(colBase + sr + 32) * ldw;

    f32x4 acc[4] = {};

    const int l15 = lane & 15, l4 = lane >> 4;
    const int ar = wid * 16 + l15;          // A row this lane reads
    const int asw = ar & 7;

    for (int kt = kbeg; kt < kend; kt += 64) {
        const bf16x8 a0 = *(const bf16x8*)(Ar0 + kt + sc8 * 8);
        const bf16x8 a1 = *(const bf16x8*)(Ar1 + kt + sc8 * 8);
        const bf16x8 b0 = *(const bf16x8*)(Wr0 + kt + sc8 * 8);
        const bf16x8 b1 = *(const bf16x8*)(Wr1 + kt + sc8 * 8);
        __syncthreads();                       // prev compute done before overwrite
        *(bf16x8*)&As[sr][wc8 * 8] = a0;
        *(bf16x8*)&As[sr + 32][wc8 * 8] = a1;
        *(bf16x8*)&Bs[sr][wc8 * 8] = b0;
        *(bf16x8*)&Bs[sr + 32][wc8 * 8] = b1;
        __syncthreads();
#pragma unroll
        for (int kk = 0; kk < 2; ++kk) {
            const int c8 = kk * 4 + l4;
            const bf16x8 af = *(const bf16x8*)&As[ar][(c8 ^ asw) * 8];
#pragma unroll
            for (int nf = 0; nf < 4; ++nf) {
                const int br = nf * 16 + l15;
                const bf16x8 bfv = *(const bf16x8*)&Bs[br][(c8 ^ (br & 7)) * 8];
                acc[nf] = __builtin_amdgcn_mfma_f32_16x16x32_bf16(af, bfv, acc[nf], 0, 0, 0);
            }
        }
    }

    // C/D layout (m89-verified): col = lane&15, row = (lane>>4)*4 + reg
    const int crow = rowBase + wid * 16 + l4 * 4;
    const int ccol = colBase + l15;
    if (Cb) {
#pragma unroll
        for (int nf = 0; nf < 4; ++nf)
#pragma unroll
            for (int r = 0; r < 4; ++r)
                Cb[(size_t)(crow + r) * O + ccol + nf * 16] = f2b(acc[nf][r]);
    } else {
        float* base = Cf + (size_t)blockIdx.z * (size_t)M * O;
#pragma unroll
        for (int nf = 0; nf < 4; ++nf)
#pragma unroll
            for (int r = 0; r < 4; ++r)
                base[(size_t)(crow + r) * O + ccol + nf * 16] = acc[nf][r];
    }
}

// reduce split-K partials: out[i] = sum_z P[z][i] (+ bias); f32 or bf16 out
__global__ void k_reduceK(const float* __restrict__ P, float* __restrict__ Cf,
                          unsigned short* __restrict__ Cb,
                          const float* __restrict__ bias, int MO4, int O4, int KS)
{
    int i = blockIdx.x * blockDim.x + threadIdx.x;
    if (i >= MO4) return;
    float4 s = make_float4(0.f, 0.f, 0.f, 0.f);
    for (int z = 0; z < KS; ++z) {
        const float4 v = reinterpret_cast<const float4*>(P)[(size_t)z * MO4 + i];
        s.x += v.x; s.y += v.y; s.z += v.z; s.w += v.w;
    }
    if (bias) {
        const float4 b = reinterpret_cast<const float4*>(bias)[i % O4];
        s.x += b.x; s.y += b.y; s.z += b.z; s.w += b.w;
    }
    if (Cb) {
        us4 o; o.x = f2b(s.x); o.y = f2b(s.y); o.z = f2b(s.z); o.w = f2b(s.w);
        *(us4*)(Cb + (size_t)i * 4) = o;
    } else {
        reinterpret_cast<float4*>(Cf)[i] = s;
    }
}

__global__ void k_copy(float* __restrict__ dst, const float* __restrict__ src, int n4)
{
    int i = blockIdx.x * blockDim.x + threadIdx.x;
    if (i < n4) reinterpret_cast<float4*>(dst)[i] = reinterpret_cast<const float4*>(src)[i];
}

// batched f32 -> bf16 conversion (weights), one launch
struct ConvBatch {
    const float* s[11];
    unsigned short* d[11];
    int beg8[11];   // cumulative start in 8-elem units
    int total8;
};
__global__ void k_f2b_batch(ConvBatch cb)
{
    int i = blockIdx.x * blockDim.x + threadIdx.x;
    if (i >= cb.total8) return;
    int k = 0;
    while (k < 10 && i >= cb.beg8[k + 1]) ++k;
    const int j = i - cb.beg8[k];
    const float4 v0 = reinterpret_cast<const float4*>(cb.s[k])[2 * j];
    const float4 v1 = reinterpret_cast<const float4*>(cb.s[k])[2 * j + 1];
    us8 o;
    o[0] = f2b(v0.x); o[1] = f2b(v0.y); o[2] = f2b(v0.z); o[3] = f2b(v0.w);
    o[4] = f2b(v1.x); o[5] = f2b(v1.y); o[6] = f2b(v1.z); o[7] = f2b(v1.w);
    *(us8*)(cb.d[k] + (size_t)j * 8) = o;
}

// out[r] = [x, c, x*c, (dsign ? c-x : x-c)] in bf16 (each width kD)
__global__ void k_joint_bf(const float* __restrict__ x, const float* __restrict__ c,
                           unsigned short* __restrict__ out, int R, int dsign)
{
    const int W4 = kD / 4;
    int idx = blockIdx.x * blockDim.x + threadIdx.x;
    if (idx >= R * W4) return;
    const int row = idx / W4, d4 = idx % W4;
    const float4 xv = reinterpret_cast<const float4*>(x)[(size_t)row * W4 + d4];
    const float4 cv = reinterpret_cast<const float4*>(c)[(size_t)row * W4 + d4];
    unsigned short* o = out + (size_t)row * 4 * kD + d4 * 4;
    us4 t;
    t.x = f2b(xv.x); t.y = f2b(xv.y); t.z = f2b(xv.z); t.w = f2b(xv.w);
    *(us4*)(o) = t;
    t.x = f2b(cv.x); t.y = f2b(cv.y); t.z = f2b(cv.z); t.w = f2b(cv.w);
    *(us4*)(o + kD) = t;
    t.x = f2b(xv.x * cv.x); t.y = f2b(xv.y * cv.y); t.z = f2b(xv.z * cv.z); t.w = f2b(xv.w * cv.w);
    *(us4*)(o + 2 * kD) = t;
    if (dsign) { t.x = f2b(cv.x - xv.x); t.y = f2b(cv.y - xv.y); t.z = f2b(cv.z - xv.z); t.w = f2b(cv.w - xv.w); }
    else       { t.x = f2b(xv.x - cv.x); t.y = f2b(xv.y - cv.y); t.z = f2b(xv.z - cv.z); t.w = f2b(xv.w - cv.w); }
    *(us4*)(o + 3 * kD) = t;
}

// out bf16 = [a | b] (f32 inputs)
__global__ void k_concat2_bf(const float* __restrict__ a, const float* __restrict__ b,
                             unsigned short* __restrict__ out, int R)
{
    const int W4 = kD / 4;
    int idx = blockIdx.x * blockDim.x + threadIdx.x;
    if (idx >= R * 2 * W4) return;
    const int row = idx / (2 * W4), c = idx % (2 * W4);
    float4 v;
    if (c < W4) v = reinterpret_cast<const float4*>(a)[(size_t)row * W4 + c];
    else        v = reinterpret_cast<const float4*>(b)[(size_t)row * W4 + (c - W4)];
    us4 t; t.x = f2b(v.x); t.y = f2b(v.y); t.z = f2b(v.z); t.w = f2b(v.w);
    *(us4*)(out + (size_t)idx * 4) = t;
}

__global__ void k_concat3_bf(const float* __restrict__ a, const float* __restrict__ b,
                             const float* __restrict__ c, unsigned short* __restrict__ out, int R)
{
    const int W4 = kD / 4;
    int idx = blockIdx.x * blockDim.x + threadIdx.x;
    if (idx >= R * 3 * W4) return;
    const int row = idx / (3 * W4), cc = idx % (3 * W4);
    float4 v;
    if (cc < W4)          v = reinterpret_cast<const float4*>(a)[(size_t)row * W4 + cc];
    else if (cc < 2 * W4) v = reinterpret_cast<const float4*>(b)[(size_t)row * W4 + (cc - W4)];
    else                  v = reinterpret_cast<const float4*>(c)[(size_t)row * W4 + (cc - 2 * W4)];
    us4 t; t.x = f2b(v.x); t.y = f2b(v.y); t.z = f2b(v.z); t.w = f2b(v.w);
    *(us4*)(out + (size_t)idx * 4) = t;
}

// relj[e] += a_s[i_e] + a_o[j_e]  (f32 RMW) and also emit bf16 copy
__global__ __launch_bounds__(256)
void k_add_so(float* __restrict__ relj, unsigned short* __restrict__ relj_b,
              const float* __restrict__ a_s, const float* __restrict__ a_o,
              const int* __restrict__ edge_idx)
{
    const int e = blockIdx.x, t = threadIdx.x;
    const int idx = edge_idx[e];
    const int i = idx >> 6, j = idx & 63;
    float4* r = reinterpret_cast<float4*>(relj + (size_t)e * kD);
    const float4 s = reinterpret_cast<const float4*>(a_s + (size_t)i * kD)[t];
    const float4 o = reinterpret_cast<const float4*>(a_o + (size_t)j * kD)[t];
    float4 v = r[t];
    v.x += s.x + o.x; v.y += s.y + o.y; v.z += s.z + o.z; v.w += s.w + o.w;
    r[t] = v;
    us4 b; b.x = f2b(v.x); b.y = f2b(v.y); b.z = f2b(v.z); b.w = f2b(v.w);
    *(us4*)(relj_b + (size_t)e * kD + t * 4) = b;
}

// s_sbj[e] = <q_s[i_e], r2s[e]>/32 ; s_obj[e] = <q_o[j_e], r2o[e]>/32
__global__ __launch_bounds__(256)
void k_scores(const float* __restrict__ qs, const float* __restrict__ qo,
              const float* __restrict__ r2s, const float* __restrict__ r2o,
              const int* __restrict__ edge_idx,
              float* __restrict__ s_sbj, float* __restrict__ s_obj)
{
    const int e = blockIdx.x, t = threadIdx.x;
    const int idx = edge_idx[e];
    const int i = idx >> 6, j = idx & 63;
    const float4 a = reinterpret_cast<const float4*>(qs + (size_t)i * kD)[t];
    const float4 b = reinterpret_cast<const float4*>(r2s + (size_t)e * kD)[t];
    const float4 c = reinterpret_cast<const float4*>(qo + (size_t)j * kD)[t];
    const float4 d = reinterpret_cast<const float4*>(r2o + (size_t)e * kD)[t];
    float vs = a.x * b.x + a.y * b.y + a.z * b.z + a.w * b.w;
    float vo = c.x * d.x + c.y * d.y + c.z * d.z + c.w * d.w;
    for (int off = 32; off; off >>= 1) {
        vs += __shfl_down(vs, off);
        vo += __shfl_down(vo, off);
    }
    __shared__ float ss[4], so[4];
    const int w = t >> 6, lane = t & 63;
    if (lane == 0) { ss[w] = vs; so[w] = vo; }
    __syncthreads();
    if (t == 0) {
        s_sbj[e] = (ss[0] + ss[1] + ss[2] + ss[3]) * 0.03125f;
        s_obj[e] = (so[0] + so[1] + so[2] + so[3]) * 0.03125f;
    }
}

__global__ void k_softmax_row(const float* __restrict__ s, float* __restrict__ w)
{
    const int i = blockIdx.x, t = threadIdx.x;  // blockDim = 16
    float v = s[i * 16 + t];
    float m = v;
    for (int off = 8; off; off >>= 1) m = fmaxf(m, __shfl_xor(m, off, 16));
    const float ex = expf(v - m);
    float sum = ex;
    for (int off = 8; off; off >>= 1) sum += __shfl_xor(sum, off, 16);
    w[i * 16 + t] = ex / sum;
}

__global__ void k_softmax_col(const float* __restrict__ s, const int* __restrict__ conn,
                              float* __restrict__ w)
{
    const int j = blockIdx.x, t = threadIdx.x;  // blockDim = 64, t = row i
    const int e = conn[t * kN + j];
    const float v = (e >= 0) ? s[e] : -1e30f;
    float m = v;
    for (int off = 32; off; off >>= 1) m = fmaxf(m, __shfl_xor(m, off));
    const float ex = (e >= 0) ? expf(v - m) : 0.f;
    float sum = ex;
    for (int off = 32; off; off >>= 1) sum += __shfl_xor(sum, off);
    if (e >= 0) w[e] = ex / sum;
}

__global__ __launch_bounds__(256)
void k_ctx1(const float* __restrict__ relj, const float* __restrict__ w,
            float* __restrict__ ctx1)
{
    const int i = blockIdx.x, t = threadIdx.x;
    float4 acc = make_float4(0.f, 0.f, 0.f, 0.f);
#pragma unroll
    for (int q = 0; q < 16; ++q) {
        const int e = i * 16 + q;
        const float wv = w[e];
        const float4 v = reinterpret_cast<const float4*>(relj + (size_t)e * kD)[t];
        acc.x += wv * v.x; acc.y += wv * v.y; acc.z += wv * v.z; acc.w += wv * v.w;
    }
    reinterpret_cast<float4*>(ctx1 + (size_t)i * kD)[t] = acc;
}

__global__ __launch_bounds__(256)
void k_ctx2(const float* __restrict__ relj, const float* __restrict__ w,
            const int* __restrict__ conn, float* __restrict__ ctx2)
{
    const int j = blockIdx.x, t = threadIdx.x;
    float4 acc = make_float4(0.f, 0.f, 0.f, 0.f);
    for (int i = 0; i < kN; ++i) {
        const int e = conn[i * kN + j];
        if (e >= 0) {
            const float wv = w[e];
            const float4 v = reinterpret_cast<const float4*>(relj + (size_t)e * kD)[t];
            acc.x += wv * v.x; acc.y += wv * v.y; acc.z += wv * v.z; acc.w += wv * v.w;
        }
    }
    reinterpret_cast<float4*>(ctx2 + (size_t)j * kD)[t] = acc;
}

// =====================================================================
extern "C" void kernel_launch(void* const* d_in, const int* in_sizes, int n_in,
                              void* d_out, int out_size, void* d_ws, size_t ws_size,
                              hipStream_t stream)
{
    const float* visual   = (const float*)d_in[0];
    const float* relvis   = (const float*)d_in[1];
    const int*   conn     = (const int*)d_in[2];
    const int*   edge_idx = (const int*)d_in[4];
    const float* W_sub    = (const float*)d_in[5];
    const float* W_obj    = (const float*)d_in[6];
    const float* W_r2s    = (const float*)d_in[7];
    const float* W_r2o    = (const float*)d_in[8];
    const float* W_joint  = (const float*)d_in[9];
    const float* W_ctx    = (const float*)d_in[10];
    const float* W_relu   = (const float*)d_in[11];  // (D,3D): Ws|Wo|Wr
    const float* W_relj   = (const float*)d_in[12];
    const float* W_relc   = (const float*)d_in[13];
    const float* W_node   = (const float*)d_in[14];
    const float* b_node   = (const float*)d_in[15];
    const float* W_factor = (const float*)d_in[16];
    (void)in_sizes; (void)n_in; (void)out_size; (void)ws_size;

    float* ws = (float*)d_ws;
    size_t off = 0;
    auto allocF = [&](size_t n) { float* p = ws + off; off += n; return p; };
    auto allocU = [&](size_t n) { return (unsigned short*)allocF((n + 1) / 2); };

    unsigned short* vjin_b   = allocU((size_t)kN * 4 * kD);
    unsigned short* bigA_b   = allocU((size_t)kE * 4 * kD);
    unsigned short* rj_b     = allocU((size_t)kE * kD);
    unsigned short* relj_b   = allocU((size_t)kE * kD);
    unsigned short* vj_b     = allocU((size_t)kN * kD);
    unsigned short* vctxin_b = allocU((size_t)kN * 3 * kD);
    unsigned short* voutin_b = allocU((size_t)kN * 2 * kD);
    float* relj = allocF((size_t)kE * kD);
    float* r2s  = allocF((size_t)kE * kD);
    float* r2o  = allocF((size_t)kE * kD);
    float* rc   = allocF((size_t)kE * kD);
    float* a_s  = allocF((size_t)kN * kD);
    float* a_o  = allocF((size_t)kN * kD);
    float* q_s  = allocF((size_t)kN * kD);
    float* q_o  = allocF((size_t)kN * kD);
    float* ctx1 = allocF((size_t)kN * kD);
    float* ctx2 = allocF((size_t)kN * kD);
    float* vctx = allocF((size_t)kN * kD);
    float* s_sbj = allocF(kE);
    float* s_obj = allocF(kE);
    float* w_sbj = allocF(kE);
    float* w_obj = allocF(kE);
    float* part  = allocF(2 * (size_t)kE * kD);   // split-K partials (max KS*M*O)
    // bf16 weights
    unsigned short* Wb_sub    = allocU((size_t)kD * kD);
    unsigned short* Wb_obj    = allocU((size_t)kD * kD);
    unsigned short* Wb_r2s    = allocU((size_t)kD * kD);
    unsigned short* Wb_r2o    = allocU((size_t)kD * kD);
    unsigned short* Wb_joint  = allocU((size_t)kD * 4 * kD);
    unsigned short* Wb_ctx    = allocU((size_t)kD * 3 * kD);
    unsigned short* Wb_relu   = allocU((size_t)kD * 3 * kD);
    unsigned short* Wb_relj   = allocU((size_t)kD * 4 * kD);
    unsigned short* Wb_relc   = allocU((size_t)kD * 2 * kD);
    unsigned short* Wb_node   = allocU((size_t)kD * 2 * kD);
    unsigned short* Wb_factor = allocU((size_t)kD * 2 * kD);

    // ---- weight conversion (one launch) ----
    {
        ConvBatch cb;
        const float* srcs[11] = {W_sub, W_obj, W_r2s, W_r2o, W_joint, W_ctx, W_relu,
                                 W_relj, W_relc, W_node, W_factor};
        unsigned short* dsts[11] = {Wb_sub, Wb_obj, Wb_r2s, Wb_r2o, Wb_joint, Wb_ctx, Wb_relu,
                                    Wb_relj, Wb_relc, Wb_node, Wb_factor};
        const int nel[11] = {kD * kD, kD * kD, kD * kD, kD * kD, kD * 4 * kD, kD * 3 * kD,
                             kD * 3 * kD, kD * 4 * kD, kD * 2 * kD, kD * 2 * kD, kD * 2 * kD};
        int cum = 0;
        for (int k = 0; k < 11; ++k) {
            cb.s[k] = srcs[k]; cb.d[k] = dsts[k]; cb.beg8[k] = cum; cum += nel[k] / 8;
        }
        cb.total8 = cum;
        hipLaunchKernelGGL(k_f2b_batch, dim3((cum + 255) / 256), dim3(256), 0, stream, cb);
    }

    auto gemm = [&](const unsigned short* A, int lda, const unsigned short* W, int ldw,
                    float* Cf, unsigned short* Cb, int M, int O, int K, int KS) {
        dim3 g(O / 64, M / 64, KS);
        hipLaunchKernelGGL(k_gemm_bf, g, dim3(256), 0, stream, A, lda, W, ldw, Cf, Cb, M, O, K, KS);
    };
    auto reduceN = [&](float* Cf, unsigned short* Cb, const float* bias, int KS) {
        hipLaunchKernelGGL(k_reduceK, dim3((kN * kD / 4 + 255) / 256), dim3(256), 0, stream,
                           part, Cf, Cb, bias, kN * kD / 4, kD / 4, KS);
    };
    auto reduceE = [&](float* Cf, unsigned short* Cb, int KS) {
        hipLaunchKernelGGL(k_reduceK, dim3((kE * kD / 4 + 255) / 256), dim3(256), 0, stream,
                           part, Cf, Cb, nullptr, kE * kD / 4, kD / 4, KS);
    };

    // init: vctx = visual, rc = rel_visual
    hipLaunchKernelGGL(k_copy, dim3((kN * kD / 4 + 255) / 256), dim3(256), 0, stream,
                       vctx, visual, kN * kD / 4);
    hipLaunchKernelGGL(k_copy, dim3((kE * kD / 4 + 255) / 256), dim3(256), 0, stream,
                       rc, relvis, kE * kD / 4);

    for (int t = 0; t < kT; ++t) {
        // vj = joint(visual, vctx) @ W_joint^T  -> bf16
        hipLaunchKernelGGL(k_joint_bf, dim3((kN * (kD / 4) + 255) / 256), dim3(256), 0, stream,
                           visual, vctx, vjin_b, kN, 1);
        gemm(vjin_b, 4 * kD, Wb_joint, 4 * kD, part, nullptr, kN, kD, 4 * kD, 8);
        reduceN(nullptr, vj_b, nullptr, 8);
        // rj = joint(rel_temp, rel_ctx) @ W_rel_joint^T -> bf16 (4th block = x - c)
        hipLaunchKernelGGL(k_joint_bf, dim3((kE * (kD / 4) + 255) / 256), dim3(256), 0, stream,
                           relvis, rc, bigA_b, kE, 0);
        gemm(bigA_b, 4 * kD, Wb_relj, 4 * kD, part, nullptr, kE, kD, 4 * kD, 2);
        reduceE(nullptr, rj_b, 2);
        // a_s = vj@Ws^T, a_o = vj@Wo^T, relj = rj@Wr^T + a_s[i] + a_o[j]
        gemm(vj_b, kD, Wb_relu,          3 * kD, part, nullptr, kN, kD, kD, 8); reduceN(a_s, nullptr, nullptr, 8);
        gemm(vj_b, kD, Wb_relu + kD,     3 * kD, part, nullptr, kN, kD, kD, 8); reduceN(a_o, nullptr, nullptr, 8);
        gemm(rj_b, kD, Wb_relu + 2 * kD, 3 * kD, relj, nullptr, kE, kD, kD, 1);
        hipLaunchKernelGGL(k_add_so, dim3(kE), dim3(256), 0, stream, relj, relj_b, a_s, a_o, edge_idx);
        // attention scores
        gemm(vj_b, kD, Wb_sub, kD, part, nullptr, kN, kD, kD, 8); reduceN(q_s, nullptr, nullptr, 8);
        gemm(vj_b, kD, Wb_obj, kD, part, nullptr, kN, kD, kD, 8); reduceN(q_o, nullptr, nullptr, 8);
        gemm(relj_b, kD, Wb_r2s, kD, r2s, nullptr, kE, kD, kD, 1);
        gemm(relj_b, kD, Wb_r2o, kD, r2o, nullptr, kE, kD, kD, 1);
        hipLaunchKernelGGL(k_scores, dim3(kE), dim3(256), 0, stream,
                           q_s, q_o, r2s, r2o, edge_idx, s_sbj, s_obj);
        hipLaunchKernelGGL(k_softmax_row, dim3(kN), dim3(16), 0, stream, s_sbj, w_sbj);
        hipLaunchKernelGGL(k_softmax_col, dim3(kN), dim3(64), 0, stream, s_obj, conn, w_obj);
        // context aggregation
        hipLaunchKernelGGL(k_ctx1, dim3(kN), dim3(256), 0, stream, relj, w_sbj, ctx1);
        hipLaunchKernelGGL(k_ctx2, dim3(kN), dim3(256), 0, stream, relj, w_obj, conn, ctx2);
        // vctx = concat(vctx, ctx1, ctx2) @ W_ctx^T
        hipLaunchKernelGGL(k_concat3_bf, dim3((kN * 3 * (kD / 4) + 255) / 256), dim3(256), 0, stream,
                           vctx, ctx1, ctx2, vctxin_b, kN);
        gemm(vctxin_b, 3 * kD, Wb_ctx, 3 * kD, part, nullptr, kN, kD, 3 * kD, 8);
        reduceN(vctx, nullptr, nullptr, 8);
        // rel_ctx = concat(rel_ctx, relj) @ W_rel_ctx^T
        hipLaunchKernelGGL(k_concat2_bf, dim3((kE * 2 * (kD / 4) + 255) / 256), dim3(256), 0, stream,
                           rc, relj, bigA_b, kE);
        gemm(bigA_b, 2 * kD, Wb_relc, 2 * kD, rc, nullptr, kE, kD, 2 * kD, 1);
    }

    float* rel_out = (float*)d_out;
    float* v_out   = (float*)d_out + (size_t)kE * kD;
    // rel_out = concat(rel_visual, rel_ctx) @ W_factor^T
    hipLaunchKernelGGL(k_concat2_bf, dim3((kE * 2 * (kD / 4) + 255) / 256), dim3(256), 0, stream,
                       relvis, rc, bigA_b, kE);
    gemm(bigA_b, 2 * kD, Wb_factor, 2 * kD, rel_out, nullptr, kE, kD, 2 * kD, 1);
    // v_out = concat(visual, vctx) @ W_node^T + b_node
    hipLaunchKernelGGL(k_concat2_bf, dim3((kN * 2 * (kD / 4) + 255) / 256), dim3(256), 0, stream,
                       visual, vctx, voutin_b, kN);
    gemm(voutin_b, 2 * kD, Wb_node, 2 * kD, part, nullptr, kN, kD, 2 * kD, 8);
    reduceN(v_out, nullptr, b_node, 8);
}